// Round 2
// baseline (1664.796 us; speedup 1.0000x reference)
//
#include <hip/hip_runtime.h>
#include <stdint.h>

#define B_DIM 16384
#define V_DIM 1024
#define H_DIM 256
#define K_STEPS 8

typedef short bf16x8 __attribute__((ext_vector_type(8)));
typedef float f32x4 __attribute__((ext_vector_type(4)));

// ---------------- Threefry-2x32-20, bit-exact JAX replica ----------------
__host__ __device__ inline uint32_t rotl32(uint32_t v, int r) {
#if defined(__HIP_DEVICE_COMPILE__)
    return __builtin_amdgcn_alignbit(v, v, (uint32_t)(32 - r));
#else
    return (v << r) | (v >> (32 - r));
#endif
}

__host__ __device__ inline void threefry2x32(uint32_t k0, uint32_t k1,
                                             uint32_t x0, uint32_t x1,
                                             uint32_t* o0, uint32_t* o1) {
    uint32_t k2 = k0 ^ k1 ^ 0x1BD11BDAu;
    x0 += k0; x1 += k1;
#define TF_RND(r) { x0 += x1; x1 = rotl32(x1, (r)); x1 ^= x0; }
    TF_RND(13) TF_RND(15) TF_RND(26) TF_RND(6)
    x0 += k1; x1 += k2 + 1u;
    TF_RND(17) TF_RND(29) TF_RND(16) TF_RND(24)
    x0 += k2; x1 += k0 + 2u;
    TF_RND(13) TF_RND(15) TF_RND(26) TF_RND(6)
    x0 += k0; x1 += k1 + 3u;
    TF_RND(17) TF_RND(29) TF_RND(16) TF_RND(24)
    x0 += k1; x1 += k2 + 4u;
    TF_RND(13) TF_RND(15) TF_RND(26) TF_RND(6)
    x0 += k2; x1 += k0 + 5u;
#undef TF_RND
    *o0 = x0; *o1 = x1;
}

// Partitionable-threefry uniform (bits = o0 ^ o1 of counter (0, e)).
__device__ inline float tf_uniform(uint32_t key0, uint32_t key1, uint32_t e) {
    uint32_t o0, o1;
    threefry2x32(key0, key1, 0u, e, &o0, &o1);
    uint32_t bits = o0 ^ o1;
    return __uint_as_float((bits >> 9) | 0x3f800000u) - 1.0f;
}

__device__ inline uint16_t bf16_rn(float f) {
    uint32_t u = __float_as_uint(f);
    uint32_t r = u + 0x7FFFu + ((u >> 16) & 1u);
    return (uint16_t)(r >> 16);
}
__device__ inline float bf16_to_f32(uint16_t h) {
    return __uint_as_float(((uint32_t)h) << 16);
}

__device__ inline void gload_lds16(const void* g, void* l) {
    __builtin_amdgcn_global_load_lds((const __attribute__((address_space(1))) uint32_t*)g,
                                     (__attribute__((address_space(3))) uint32_t*)l, 16, 0, 0);
}

struct KeyPack { uint32_t hk0[8], hk1[8], vk0[8], vk1[8]; };

// ---------------- Fused Gibbs chain ----------------
// Changes vs R1:
//  * Merged, XOR-swizzled LDS tiles (conflict-free frag reads):
//      B-tile Bm[256 rows][256 B]: slot(0..15) = {s(k-half) b3, hl b2, q b1:0},
//      swizzle slot ^= (row & 15).  A-tile Am[32 rows][128 B]: slot(0..7) =
//      {s b2, q b1:0}, swizzle slot ^= (row & 7).  Staging keeps LINEAR
//      global_load_lds destinations and pre-swizzles the per-lane GLOBAL
//      source address (m173 pattern, rule #21 both-sides).
//  * RNG precompute: uniforms are data-independent, so 16 h-draws + 32 of 64
//    v-draws per thread are computed inside the (fully unrolled) k0 loop,
//    3 per iteration, filling phase A's staging-latency windows.
// Accumulation order, sampling logic and threefry counters are bit-identical.
__global__ __launch_bounds__(512, 4) void gibbs_fused(
    const ushort* __restrict__ batch_bf,
    const ushort* __restrict__ Whi, const ushort* __restrict__ Wlo,
    const float* __restrict__ Wf, const float* __restrict__ vb,
    const float* __restrict__ hb, ushort* __restrict__ v_cur,
    ushort* __restrict__ ph0b, ushort* __restrict__ phkb, KeyPack kp) {
    __shared__ __align__(16) ushort Am[32 * 64];     // 4 KB  [32][128 B]
    __shared__ __align__(16) ushort Bm[256 * 128];   // 64 KB [256][256 B]

    const int tid = threadIdx.x;
    const int lane = tid & 63;
    const int w = tid >> 6;            // 0..7
    const int m0 = blockIdx.x * 32;

    const int wm = (w & 1) * 16;       // M sub-tile (16 rows)
    const int wn = (w >> 1) * 64;      // N sub-tile (64 cols)
    const int q = lane >> 4;
    const int l15 = lane & 15;

    // ---- staging source precompute (k0-invariant, per lane) ----
    // B: wave w stages chunks w*8+c (c=0..7), each 4 rows x 256 B.
    const ushort* bsrc[8];
#pragma unroll
    for (int c = 0; c < 8; ++c) {
        const int row = w * 32 + c * 4 + (lane >> 4);
        const int slot = lane & 15;
        const int us = slot ^ (row & 15);       // unswizzled slot
        const int hl = (us >> 2) & 1;
        const int s = us >> 3;
        const int qq = us & 3;
        bsrc[c] = (hl ? Wlo : Whi) + (size_t)row * V_DIM + s * 32 + qq * 8;
    }
    // A: waves 0..3 stage 8 rows x 128 B each.
    size_t a_src_off;
    {
        const int arow = w * 8 + (lane >> 3);
        const int aslot = lane & 7;
        const int us = aslot ^ (arow & 7);
        const int s = us >> 2;
        const int qq = us & 3;
        a_src_off = (size_t)(m0 + arow) * V_DIM + s * 32 + qq * 8;
    }

    // ---- fragment-read swizzled byte offsets (k0-invariant) ----
    const int arow_ = wm + l15;                       // A frag row 0..31
    const int aqxl = (q * 16) ^ ((l15 & 7) << 4);     // A col-swizzle
    const int qxl = (q * 16) ^ (l15 << 4);            // B col-swizzle

    ushort* h_lds = &Bm[0];            // [32][256] bits, valid after phase A

    float uh[16];                      // h-uniforms (j*4+r)
    float uv[32];                      // v-uniforms for rr=0,1 (rr*16+t)

    for (int step = 0; step <= K_STEPS; ++step) {
        const ushort* Asrc = (step == 0) ? batch_bf : v_cur;
        uint32_t kh0s = 0, kh1s = 0, kv0s = 0, kv1s = 0;
        if (step < K_STEPS) {
            kh0s = kp.hk0[step]; kh1s = kp.hk1[step];
            kv0s = kp.vk0[step]; kv1s = kp.vk1[step];
        }
        f32x4 acc[4] = {};

#pragma unroll
        for (int k0i = 0; k0i < 16; ++k0i) {
            const int k0 = k0i * 64;
            if (w < 4) gload_lds16(Asrc + a_src_off + k0, &Am[w * 512]);
#pragma unroll
            for (int c = 0; c < 8; ++c)
                gload_lds16(bsrc[c] + k0, &Bm[(w * 8 + c) * 512]);
            __syncthreads();

#pragma unroll
            for (int s = 0; s < 2; ++s) {
                bf16x8 af = *(const bf16x8*)((const char*)Am + arow_ * 128 + ((s * 64) ^ aqxl));
#pragma unroll
                for (int j = 0; j < 4; ++j) {
                    const char* bbase = (const char*)Bm + (wn + j * 16 + l15) * 256;
                    bf16x8 bh = *(const bf16x8*)(bbase + ((s * 128) ^ qxl));
                    bf16x8 bl = *(const bf16x8*)(bbase + ((s * 128 + 64) ^ qxl));
                    acc[j] = __builtin_amdgcn_mfma_f32_16x16x32_bf16(af, bh, acc[j], 0, 0, 0);
                    acc[j] = __builtin_amdgcn_mfma_f32_16x16x32_bf16(af, bl, acc[j], 0, 0, 0);
                }
            }

            // ---- RNG precompute, 3 uniforms per iter (data-independent) ----
            if (step < K_STEPS) {
#pragma unroll
                for (int uu = 0; uu < 3; ++uu) {
                    const int idx = k0i * 3 + uu;   // 0..47, static under unroll
                    if (idx < 16) {
                        const int j = idx >> 2, r = idx & 3;
                        const uint32_t e =
                            (uint32_t)(m0 + wm + q * 4 + r) * (uint32_t)H_DIM +
                            (uint32_t)(wn + j * 16 + l15);
                        uh[idx] = tf_uniform(kh0s, kh1s, e);
                    } else {
                        const int iv = idx - 16;
                        const int rr = iv >> 4, t = iv & 15;
                        const uint32_t e =
                            (uint32_t)(m0 + w * 4 + rr) * (uint32_t)V_DIM +
                            (uint32_t)lane + 64u * (uint32_t)t;
                        uv[iv] = tf_uniform(kv0s, kv1s, e);
                    }
                }
            }
            __syncthreads();
        }

        if (step == K_STEPS) {
            // final phk = sigmoid(pre_k), precise divide, bf16
#pragma unroll
            for (int j = 0; j < 4; ++j) {
                const int col = wn + j * 16 + l15;
                const float hbv = hb[col];
#pragma unroll
                for (int r = 0; r < 4; ++r) {
                    const int row = m0 + wm + q * 4 + r;
                    float val = acc[j][r] + hbv;
                    phkb[(size_t)row * H_DIM + col] = bf16_rn(1.0f / (1.0f + expf(-val)));
                }
            }
            break;  // uniform across block
        }

        // ---- phase B: sample h into LDS (and ph0 at step 0) ----
#pragma unroll
        for (int j = 0; j < 4; ++j) {
            const int col = wn + j * 16 + l15;
            const float hbv = hb[col];
#pragma unroll
            for (int r = 0; r < 4; ++r) {
                const int rowl = wm + q * 4 + r;
                const int row = m0 + rowl;
                float val = acc[j][r] + hbv;
                float E = expf(-val);
                float u = uh[j * 4 + r];
                // u < 1/(1+E)  <=>  fma(u,E,u) < 1
                h_lds[rowl * H_DIM + col] = (fmaf(u, E, u) < 1.0f) ? (ushort)0x3F80 : (ushort)0;
                if (step == 0) {
                    ph0b[(size_t)row * H_DIM + col] = bf16_rn(1.0f / (1.0f + E));
                }
            }
        }
        __syncthreads();

        // ---- phase C: sparse v-side sampler ----
        float vbr[16];
#pragma unroll
        for (int t = 0; t < 16; ++t) vbr[t] = vb[lane + 64 * t];
#pragma unroll
        for (int rr = 0; rr < 4; ++rr) {
            const int bl_ = w * 4 + rr;     // local row 0..31
            const int b = m0 + bl_;
            ushort4 hv = ((const ushort4*)(h_lds + bl_ * H_DIM))[lane];
            unsigned long long masks[4];
            masks[0] = __ballot(hv.x != 0);
            masks[1] = __ballot(hv.y != 0);
            masks[2] = __ballot(hv.z != 0);
            masks[3] = __ballot(hv.w != 0);

            float acc2[16];
#pragma unroll
            for (int t = 0; t < 16; ++t) acc2[t] = 0.0f;

#pragma unroll
            for (int s = 0; s < 4; ++s) {
                unsigned long long m = masks[s];
                while (m) {  // wave-uniform loop, no divergence
                    int l = __ffsll(m) - 1;
                    m &= m - 1;
                    int jj = l * 4 + s;
                    const float* wrow = Wf + (size_t)jj * V_DIM + lane;
#pragma unroll
                    for (int t = 0; t < 16; ++t) acc2[t] += wrow[64 * t];
                }
            }

            const uint32_t ebase = (uint32_t)b * (uint32_t)V_DIM + (uint32_t)lane;
            ushort* orow = v_cur + (size_t)b * V_DIM + lane;
#pragma unroll
            for (int t = 0; t < 16; ++t) {
                float pre = acc2[t] + vbr[t];
                float E = expf(-pre);
                float u = (rr < 2) ? uv[rr * 16 + t]
                                   : tf_uniform(kv0s, kv1s, ebase + 64u * (uint32_t)t);
                orow[64 * t] = (fmaf(u, E, u) < 1.0f) ? (ushort)0x3F80 : (ushort)0;
            }
        }
        __syncthreads();  // v_cur stores drained before re-staging
    }
}

// ---------------- LDS MFMA NT-GEMM accumulate (gw) ----------------
__global__ __launch_bounds__(256, 4) void mfma_gemm_acc(
    const ushort* __restrict__ A, const ushort* __restrict__ Bt,
    float* __restrict__ out, int N, int K, int k_slice) {
    __shared__ __align__(16) ushort As[64 * 32];
    __shared__ __align__(16) ushort Bs[64 * 32];

    const int tid = threadIdx.x;
    const int lane = tid & 63;
    const int w = tid >> 6;
    const int m0 = blockIdx.x * 64;
    const int n0 = blockIdx.y * 64;
    const int kbase = blockIdx.z * k_slice;

    f32x4 acc[2][2] = {};

    const int wm = (w & 1) * 32;
    const int wn = (w >> 1) * 32;
    const int q = lane >> 4;
    const int l15 = lane & 15;
    const int srow = lane >> 2;
    const int scol = (lane & 3) * 8;

    const size_t arow = (size_t)(m0 + w * 16 + srow) * K;
    const size_t brow = (size_t)(n0 + w * 16 + srow) * K;

    for (int kt = 0; kt < k_slice; kt += 32) {
        const int k0 = kbase + kt;
        gload_lds16(&A[arow + k0 + scol], &As[w * 512]);
        gload_lds16(&Bt[brow + k0 + scol], &Bs[w * 512]);
        __syncthreads();
        bf16x8 af[2], bf[2];
#pragma unroll
        for (int i = 0; i < 2; ++i) {
            af[i] = *(const bf16x8*)&As[(wm + i * 16 + l15) * 32 + q * 8];
            bf[i] = *(const bf16x8*)&Bs[(wn + i * 16 + l15) * 32 + q * 8];
        }
#pragma unroll
        for (int i = 0; i < 2; ++i)
#pragma unroll
            for (int j = 0; j < 2; ++j)
                acc[i][j] = __builtin_amdgcn_mfma_f32_16x16x32_bf16(af[i], bf[j], acc[i][j], 0, 0, 0);
        __syncthreads();
    }

    const int orow = q * 4;
#pragma unroll
    for (int i = 0; i < 2; ++i)
#pragma unroll
        for (int j = 0; j < 2; ++j) {
            int col = n0 + wn + j * 16 + l15;
#pragma unroll
            for (int r = 0; r < 4; ++r) {
                int row = m0 + wm + i * 16 + orow + r;
                atomicAdd(&out[(size_t)row * N + col], acc[i][j][r]);
            }
        }
}

// ---------------- W split into bf16 hi/lo ----------------
__global__ void wsplit_kernel(const float* __restrict__ W, ushort* __restrict__ whi,
                              ushort* __restrict__ wlo) {
    int idx = blockIdx.x * 256 + threadIdx.x;
    float w = W[idx];
    ushort hi = bf16_rn(w);
    float fhi = bf16_to_f32(hi);
    ushort lo = bf16_rn(w - fhi);
    whi[idx] = hi; wlo[idx] = lo;
}

__global__ void tobf16_kernel(const float* __restrict__ src, ushort* __restrict__ dst) {
    int idx = blockIdx.x * 256 + threadIdx.x;
    float4 f = ((const float4*)src)[idx];
    ushort4 o;
    o.x = bf16_rn(f.x); o.y = bf16_rn(f.y); o.z = bf16_rn(f.z); o.w = bf16_rn(f.w);
    ((ushort4*)dst)[idx] = o;
}

// ---------------- log-norm ----------------
__global__ __launch_bounds__(256) void lognorm_kernel(
    const ushort* __restrict__ phk, const ushort* __restrict__ vk,
    const float* __restrict__ vb, float* __restrict__ inv) {
    int b = blockIdx.x;
    int tid = threadIdx.x;
    float p = bf16_to_f32(phk[(size_t)b * H_DIM + tid]);
    float s = -log1pf(-p);
    for (int j = tid; j < V_DIM; j += 256)
        s += bf16_to_f32(vk[(size_t)b * V_DIM + j]) * vb[j];
    for (int off = 32; off > 0; off >>= 1) s += __shfl_down(s, off, 64);
    __shared__ float wsum[4];
    int lane = tid & 63, wid = tid >> 6;
    if (lane == 0) wsum[wid] = s;
    __syncthreads();
    if (tid == 0) {
        float t = wsum[0] + wsum[1] + wsum[2] + wsum[3];
        inv[b] = expf(-t) * (1.0f / 16384.0f);
    }
}

// ---------------- transposes for gw GEMM ----------------
__global__ void build_At(const ushort* __restrict__ P, const float* __restrict__ inv,
                         float sgn, ushort* __restrict__ At) {
    __shared__ float T[64][65];
    int c = threadIdx.x & 63;
    int rb = threadIdx.x >> 6;
    int b0 = blockIdx.x * 64;
    int h0 = blockIdx.y * 64;
    for (int r = rb; r < 64; r += 4) {
        int b = b0 + r;
        T[c][r] = sgn * inv[b] * bf16_to_f32(P[(size_t)b * H_DIM + h0 + c]);
    }
    __syncthreads();
    for (int r = rb; r < 64; r += 4)
        At[(size_t)(h0 + r) * B_DIM + b0 + c] = bf16_rn(T[r][c]);
}

__global__ void build_Bt(const ushort* __restrict__ Sb, const float* __restrict__ Sf,
                         int use_f32, ushort* __restrict__ Bt) {
    __shared__ ushort T[64][65];
    int c = threadIdx.x & 63;
    int rb = threadIdx.x >> 6;
    int b0 = blockIdx.x * 64;
    int v0 = blockIdx.y * 64;
    for (int r = rb; r < 64; r += 4) {
        int b = b0 + r;
        T[c][r] = use_f32 ? bf16_rn(Sf[(size_t)b * V_DIM + v0 + c])
                          : Sb[(size_t)b * V_DIM + v0 + c];
    }
    __syncthreads();
    for (int r = rb; r < 64; r += 4)
        Bt[(size_t)(v0 + r) * B_DIM + b0 + c] = T[r][c];
}

// ---------------- g_vb / g_hb ----------------
__global__ void gvb_kernel(const ushort* __restrict__ vk, const ushort* __restrict__ vbat,
                           const float* __restrict__ inv, float* __restrict__ gvb) {
    int col = blockIdx.x * 256 + threadIdx.x;
    int b0 = blockIdx.y * 512;
    float acc = 0.0f;
    for (int r = 0; r < 512; ++r) {
        int b = b0 + r;
        acc += inv[b] * (bf16_to_f32(vk[(size_t)b * V_DIM + col]) -
                         bf16_to_f32(vbat[(size_t)b * V_DIM + col]));
    }
    atomicAdd(&gvb[col], acc);
}

__global__ void ghb_kernel(const ushort* __restrict__ phk, const ushort* __restrict__ ph0,
                           const float* __restrict__ inv, float* __restrict__ ghb) {
    int col = threadIdx.x;
    int b0 = blockIdx.x * 256;
    float acc = 0.0f;
    for (int r = 0; r < 256; ++r) {
        int b = b0 + r;
        acc += inv[b] * (bf16_to_f32(phk[(size_t)b * H_DIM + col]) -
                         bf16_to_f32(ph0[(size_t)b * H_DIM + col]));
    }
    atomicAdd(&ghb[col], acc);
}

extern "C" void kernel_launch(void* const* d_in, const int* in_sizes, int n_in,
                              void* d_out, int out_size, void* d_ws, size_t ws_size,
                              hipStream_t stream) {
    const float* batch = (const float*)d_in[0];
    const float* W = (const float*)d_in[1];
    const float* vb = (const float*)d_in[2];
    const float* hb = (const float*)d_in[3];

    char* base = (char*)d_ws;
    ushort* w_hi  = (ushort*)(base + 0);          // 512 KB
    ushort* w_lo  = (ushort*)(base + 524288);
    ushort* v_cur = (ushort*)(base + 2097152);    // 32 MB
    float*  inv   = (float*)(base + 35651584);    // 64 KB
    ushort* At    = (ushort*)(base + 35717120);   // 8 MB
    ushort* batch_bf = (ushort*)(base + 44105728); // 32 MB (aliased: Bt after last use)
    ushort* Bt    = batch_bf;
    ushort* ph0b  = (ushort*)(base + 77660160);   // 8 MB
    ushort* phkb  = (ushort*)(base + 86048768);   // 8 MB -> total 94437376 B

    float* gw  = (float*)d_out;
    float* gvb = gw + (size_t)H_DIM * V_DIM;
    float* ghb = gvb + V_DIM;

    hipMemsetAsync(d_out, 0, (size_t)out_size * sizeof(float), stream);

    // Partitionable threefry split of key(42): subkey[n] = threefry((0,42),(0,n)).
    KeyPack kp;
    for (int i = 0; i < K_STEPS; ++i) {
        threefry2x32(0u, 42u, 0u, (uint32_t)(2 * i),     &kp.hk0[i], &kp.hk1[i]);
        threefry2x32(0u, 42u, 0u, (uint32_t)(2 * i + 1), &kp.vk0[i], &kp.vk1[i]);
    }

    wsplit_kernel<<<dim3(1024), dim3(256), 0, stream>>>(W, w_hi, w_lo);
    tobf16_kernel<<<dim3(B_DIM * V_DIM / 4 / 256), dim3(256), 0, stream>>>(batch, batch_bf);

    // Entire k=8 Gibbs chain + final phk pass, fused (rows are independent).
    gibbs_fused<<<dim3(B_DIM / 32), dim3(512), 0, stream>>>(
        batch_bf, w_hi, w_lo, W, vb, hb, v_cur, ph0b, phkb, kp);

    lognorm_kernel<<<dim3(B_DIM), dim3(256), 0, stream>>>(phkb, v_cur, vb, inv);
    ghb_kernel<<<dim3(B_DIM / 256), dim3(256), 0, stream>>>(phkb, ph0b, inv, ghb);
    gvb_kernel<<<dim3(V_DIM / 256, B_DIM / 512), dim3(256), 0, stream>>>(v_cur, batch_bf, inv, gvb);

    // g_W positive phase
    build_At<<<dim3(B_DIM / 64, H_DIM / 64), dim3(256), 0, stream>>>(phkb, inv, 1.0f, At);
    build_Bt<<<dim3(B_DIM / 64, V_DIM / 64), dim3(256), 0, stream>>>(v_cur, nullptr, 0, Bt);
    mfma_gemm_acc<<<dim3(H_DIM / 64, V_DIM / 64, 16), dim3(256), 0, stream>>>(
        At, Bt, gw, V_DIM, B_DIM, 1024);
    // g_W negative phase
    build_At<<<dim3(B_DIM / 64, H_DIM / 64), dim3(256), 0, stream>>>(ph0b, inv, -1.0f, At);
    build_Bt<<<dim3(B_DIM / 64, V_DIM / 64), dim3(256), 0, stream>>>(nullptr, batch, 1, Bt);
    mfma_gemm_acc<<<dim3(H_DIM / 64, V_DIM / 64, 16), dim3(256), 0, stream>>>(
        At, Bt, gw, V_DIM, B_DIM, 1024);
}

// Round 3
// 1260.724 us; speedup vs baseline: 1.3205x; 1.3205x over previous
//
#include <hip/hip_runtime.h>
#include <stdint.h>

#define B_DIM 16384
#define V_DIM 1024
#define H_DIM 256
#define K_STEPS 8

typedef short bf16x8 __attribute__((ext_vector_type(8)));
typedef float f32x4 __attribute__((ext_vector_type(4)));

// ---------------- Threefry-2x32-20, bit-exact JAX replica ----------------
__host__ __device__ inline uint32_t rotl32(uint32_t v, int r) {
#if defined(__HIP_DEVICE_COMPILE__)
    return __builtin_amdgcn_alignbit(v, v, (uint32_t)(32 - r));
#else
    return (v << r) | (v >> (32 - r));
#endif
}

__host__ __device__ inline void threefry2x32(uint32_t k0, uint32_t k1,
                                             uint32_t x0, uint32_t x1,
                                             uint32_t* o0, uint32_t* o1) {
    uint32_t k2 = k0 ^ k1 ^ 0x1BD11BDAu;
    x0 += k0; x1 += k1;
#define TF_RND(r) { x0 += x1; x1 = rotl32(x1, (r)); x1 ^= x0; }
    TF_RND(13) TF_RND(15) TF_RND(26) TF_RND(6)
    x0 += k1; x1 += k2 + 1u;
    TF_RND(17) TF_RND(29) TF_RND(16) TF_RND(24)
    x0 += k2; x1 += k0 + 2u;
    TF_RND(13) TF_RND(15) TF_RND(26) TF_RND(6)
    x0 += k0; x1 += k1 + 3u;
    TF_RND(17) TF_RND(29) TF_RND(16) TF_RND(24)
    x0 += k1; x1 += k2 + 4u;
    TF_RND(13) TF_RND(15) TF_RND(26) TF_RND(6)
    x0 += k2; x1 += k0 + 5u;
#undef TF_RND
    *o0 = x0; *o1 = x1;
}

// Partitionable-threefry uniform (bits = o0 ^ o1 of counter (0, e)).
__device__ inline float tf_uniform(uint32_t key0, uint32_t key1, uint32_t e) {
    uint32_t o0, o1;
    threefry2x32(key0, key1, 0u, e, &o0, &o1);
    uint32_t bits = o0 ^ o1;
    return __uint_as_float((bits >> 9) | 0x3f800000u) - 1.0f;
}

__device__ inline uint16_t bf16_rn(float f) {
    uint32_t u = __float_as_uint(f);
    uint32_t r = u + 0x7FFFu + ((u >> 16) & 1u);
    return (uint16_t)(r >> 16);
}
__device__ inline float bf16_to_f32(uint16_t h) {
    return __uint_as_float(((uint32_t)h) << 16);
}

__device__ inline void gload_lds16(const void* g, void* l) {
    __builtin_amdgcn_global_load_lds((const __attribute__((address_space(1))) uint32_t*)g,
                                     (__attribute__((address_space(3))) uint32_t*)l, 16, 0, 0);
}

struct KeyPack { uint32_t hk0[8], hk1[8], vk0[8], vk1[8]; };

// ---------------- Fused Gibbs chain ----------------
// R3 structure:
//  * BK=32 merged hi/lo W-tile Bm[256 rows][128 B], XOR-swizzled (slot ^= row&7)
//    with pre-swizzled global source addresses (verified in R2: conflicts 41x down).
//  * v kept BIT-PACKED in LDS (Bv[32][32] u32 words, col ^= row&31 swizzle),
//    built via __ballot in phase C; phase A expands bits -> bf16 {0,0x3F80}
//    fragments in registers. No A-tile staging, no per-step v_cur global
//    round-trip (global v store only at step 7, for the tail kernels).
//  * LDS = 32KB + 4KB -> 4 blocks/CU: inter-block phase diversity overlaps
//    one block's RNG VALU with another's staging/MFMA.
//  * RNG computed inline in phases B/C (R1 scheme; R2's precompute arrays
//    spilled to scratch and are reverted).
// MFMA inputs and accumulation order (k ascending, hi then lo) are bit-identical
// to R1/R2, so all samples and outputs are unchanged.
__global__ __launch_bounds__(512, 2) void gibbs_fused(
    const ushort* __restrict__ batch_bf,
    const ushort* __restrict__ Whi, const ushort* __restrict__ Wlo,
    const float* __restrict__ Wf, const float* __restrict__ vb,
    const float* __restrict__ hb, ushort* __restrict__ v_cur,
    ushort* __restrict__ ph0b, ushort* __restrict__ phkb, KeyPack kp) {
    __shared__ __align__(16) ushort Bm[256 * 64];   // 32 KB [256 rows][128 B]
    __shared__ uint32_t Bv[32 * 32];                // 4 KB bit-packed v (swizzled cols)

    const int tid = threadIdx.x;
    const int lane = tid & 63;
    const int w = tid >> 6;            // 0..7
    const int m0 = blockIdx.x * 32;

    const int wm = (w & 1) * 16;       // M sub-tile (16 rows)
    const int wn = (w >> 1) * 64;      // N sub-tile (64 cols)
    const int q = lane >> 4;
    const int l15 = lane & 15;
    const int ra = wm + l15;           // A-frag local row 0..31

    // ---- B staging source precompute (k0-invariant, per lane) ----
    // chunk c: rows w*32 + c*8 + (lane>>3), stored slot = lane&7,
    // logical slot = stored ^ (row&7); logical = hl*4 + qq.
    const ushort* bsrc[4];
#pragma unroll
    for (int c = 0; c < 4; ++c) {
        const int row = w * 32 + c * 8 + (lane >> 3);
        const int sl = (lane & 7) ^ (row & 7);
        const int hl = sl >> 2;
        const int qq = sl & 3;
        bsrc[c] = (hl ? Wlo : Whi) + (size_t)row * V_DIM + qq * 8;
    }

    ushort* h_lds = &Bm[0];            // [32][256] h bits, alias (phase B->C only)

    // ---- prologue: pack batch bits into Bv ----
#pragma unroll
    for (int rr = 0; rr < 4; ++rr) {
        const int row = w * 4 + rr;
        const ushort* brp = batch_bf + (size_t)(m0 + row) * V_DIM;
#pragma unroll
        for (int t = 0; t < 16; ++t) {
            bool dec = brp[lane + 64 * t] != 0;
            unsigned long long bal = __ballot(dec);
            if ((lane >> 1) == t) {
                uint32_t val = (lane & 1) ? (uint32_t)(bal >> 32) : (uint32_t)bal;
                Bv[row * 32 + ((2 * t + (lane & 1)) ^ (row & 31))] = val;
            }
        }
    }
    __syncthreads();

    for (int step = 0; step <= K_STEPS; ++step) {
        f32x4 acc[4] = {};

        for (int k0i = 0; k0i < 32; ++k0i) {
            const int k0 = k0i * 32;
#pragma unroll
            for (int c = 0; c < 4; ++c)
                gload_lds16(bsrc[c] + k0, &Bm[(w * 32 + c * 8) * 64]);
            __syncthreads();

            // A fragment from bit-packed v (8 consecutive k = byte q of word k0i)
            const uint32_t vw = Bv[ra * 32 + (k0i ^ (ra & 31))];
            const uint32_t bq = (vw >> (q * 8)) & 0xffu;
            bf16x8 af;
#pragma unroll
            for (int e = 0; e < 8; ++e)
                af[e] = (short)(((bq >> e) & 1u) ? 0x3F80 : 0);

#pragma unroll
            for (int j = 0; j < 4; ++j) {
                const int rb = wn + j * 16 + l15;
                const char* bb = (const char*)Bm + rb * 128;
                const int st = (q ^ (rb & 7)) * 16;
                bf16x8 bh = *(const bf16x8*)(bb + st);
                bf16x8 bl = *(const bf16x8*)(bb + (st ^ 64));
                acc[j] = __builtin_amdgcn_mfma_f32_16x16x32_bf16(af, bh, acc[j], 0, 0, 0);
                acc[j] = __builtin_amdgcn_mfma_f32_16x16x32_bf16(af, bl, acc[j], 0, 0, 0);
            }
            __syncthreads();
        }

        if (step == K_STEPS) {
            // final phk = sigmoid(pre_k), precise divide, bf16
#pragma unroll
            for (int j = 0; j < 4; ++j) {
                const int col = wn + j * 16 + l15;
                const float hbv = hb[col];
#pragma unroll
                for (int r = 0; r < 4; ++r) {
                    const int row = m0 + wm + q * 4 + r;
                    float val = acc[j][r] + hbv;
                    phkb[(size_t)row * H_DIM + col] = bf16_rn(1.0f / (1.0f + expf(-val)));
                }
            }
            break;  // uniform across block
        }

        // ---- phase B: sample h into LDS (and ph0 at step 0) ----
        const uint32_t kh0s = kp.hk0[step], kh1s = kp.hk1[step];
#pragma unroll
        for (int j = 0; j < 4; ++j) {
            const int col = wn + j * 16 + l15;
            const float hbv = hb[col];
#pragma unroll
            for (int r = 0; r < 4; ++r) {
                const int rowl = wm + q * 4 + r;
                const int row = m0 + rowl;
                float val = acc[j][r] + hbv;
                float E = expf(-val);
                float u = tf_uniform(kh0s, kh1s,
                                     (uint32_t)row * (uint32_t)H_DIM + (uint32_t)col);
                // u < 1/(1+E)  <=>  fma(u,E,u) < 1
                h_lds[rowl * H_DIM + col] = (fmaf(u, E, u) < 1.0f) ? (ushort)0x3F80 : (ushort)0;
                if (step == 0) {
                    ph0b[(size_t)row * H_DIM + col] = bf16_rn(1.0f / (1.0f + E));
                }
            }
        }
        __syncthreads();

        // ---- phase C: sparse v-side sampler; v -> Bv bits (global store at last step) ----
        const uint32_t kv0s = kp.vk0[step], kv1s = kp.vk1[step];
        float vbr[16];
#pragma unroll
        for (int t = 0; t < 16; ++t) vbr[t] = vb[lane + 64 * t];
#pragma unroll
        for (int rr = 0; rr < 4; ++rr) {
            const int bl_ = w * 4 + rr;     // local row 0..31
            const int b = m0 + bl_;
            ushort4 hv = ((const ushort4*)(h_lds + bl_ * H_DIM))[lane];
            unsigned long long masks[4];
            masks[0] = __ballot(hv.x != 0);
            masks[1] = __ballot(hv.y != 0);
            masks[2] = __ballot(hv.z != 0);
            masks[3] = __ballot(hv.w != 0);

            float acc2[16];
#pragma unroll
            for (int t = 0; t < 16; ++t) acc2[t] = 0.0f;

#pragma unroll
            for (int s = 0; s < 4; ++s) {
                unsigned long long m = masks[s];
                while (m) {  // wave-uniform loop, no divergence
                    int l = __ffsll(m) - 1;
                    m &= m - 1;
                    int jj = l * 4 + s;
                    const float* wrow = Wf + (size_t)jj * V_DIM + lane;
#pragma unroll
                    for (int t = 0; t < 16; ++t) acc2[t] += wrow[64 * t];
                }
            }

            const uint32_t ebase = (uint32_t)b * (uint32_t)V_DIM + (uint32_t)lane;
            ushort* orow = v_cur + (size_t)b * V_DIM + lane;
#pragma unroll
            for (int t = 0; t < 16; ++t) {
                float pre = acc2[t] + vbr[t];
                float E = expf(-pre);
                float u = tf_uniform(kv0s, kv1s, ebase + 64u * (uint32_t)t);
                bool dec = (fmaf(u, E, u) < 1.0f);
                if (step == K_STEPS - 1) orow[64 * t] = dec ? (ushort)0x3F80 : (ushort)0;
                unsigned long long bal = __ballot(dec);
                if ((lane >> 1) == t) {
                    uint32_t val = (lane & 1) ? (uint32_t)(bal >> 32) : (uint32_t)bal;
                    Bv[bl_ * 32 + ((2 * t + (lane & 1)) ^ (bl_ & 31))] = val;
                }
            }
        }
        __syncthreads();  // Bv (and last-step v_cur) visible before next phase A
    }
}

// ---------------- LDS MFMA NT-GEMM accumulate (gw) ----------------
__global__ __launch_bounds__(256, 4) void mfma_gemm_acc(
    const ushort* __restrict__ A, const ushort* __restrict__ Bt,
    float* __restrict__ out, int N, int K, int k_slice) {
    __shared__ __align__(16) ushort As[64 * 32];
    __shared__ __align__(16) ushort Bs[64 * 32];

    const int tid = threadIdx.x;
    const int lane = tid & 63;
    const int w = tid >> 6;
    const int m0 = blockIdx.x * 64;
    const int n0 = blockIdx.y * 64;
    const int kbase = blockIdx.z * k_slice;

    f32x4 acc[2][2] = {};

    const int wm = (w & 1) * 32;
    const int wn = (w >> 1) * 32;
    const int q = lane >> 4;
    const int l15 = lane & 15;
    const int srow = lane >> 2;
    const int scol = (lane & 3) * 8;

    const size_t arow = (size_t)(m0 + w * 16 + srow) * K;
    const size_t brow = (size_t)(n0 + w * 16 + srow) * K;

    for (int kt = 0; kt < k_slice; kt += 32) {
        const int k0 = kbase + kt;
        gload_lds16(&A[arow + k0 + scol], &As[w * 512]);
        gload_lds16(&Bt[brow + k0 + scol], &Bs[w * 512]);
        __syncthreads();
        bf16x8 af[2], bf[2];
#pragma unroll
        for (int i = 0; i < 2; ++i) {
            af[i] = *(const bf16x8*)&As[(wm + i * 16 + l15) * 32 + q * 8];
            bf[i] = *(const bf16x8*)&Bs[(wn + i * 16 + l15) * 32 + q * 8];
        }
#pragma unroll
        for (int i = 0; i < 2; ++i)
#pragma unroll
            for (int j = 0; j < 2; ++j)
                acc[i][j] = __builtin_amdgcn_mfma_f32_16x16x32_bf16(af[i], bf[j], acc[i][j], 0, 0, 0);
        __syncthreads();
    }

    const int orow = q * 4;
#pragma unroll
    for (int i = 0; i < 2; ++i)
#pragma unroll
        for (int j = 0; j < 2; ++j) {
            int col = n0 + wn + j * 16 + l15;
#pragma unroll
            for (int r = 0; r < 4; ++r) {
                int row = m0 + wm + i * 16 + orow + r;
                atomicAdd(&out[(size_t)row * N + col], acc[i][j][r]);
            }
        }
}

// ---------------- W split into bf16 hi/lo ----------------
__global__ void wsplit_kernel(const float* __restrict__ W, ushort* __restrict__ whi,
                              ushort* __restrict__ wlo) {
    int idx = blockIdx.x * 256 + threadIdx.x;
    float w = W[idx];
    ushort hi = bf16_rn(w);
    float fhi = bf16_to_f32(hi);
    ushort lo = bf16_rn(w - fhi);
    whi[idx] = hi; wlo[idx] = lo;
}

__global__ void tobf16_kernel(const float* __restrict__ src, ushort* __restrict__ dst) {
    int idx = blockIdx.x * 256 + threadIdx.x;
    float4 f = ((const float4*)src)[idx];
    ushort4 o;
    o.x = bf16_rn(f.x); o.y = bf16_rn(f.y); o.z = bf16_rn(f.z); o.w = bf16_rn(f.w);
    ((ushort4*)dst)[idx] = o;
}

// ---------------- log-norm ----------------
__global__ __launch_bounds__(256) void lognorm_kernel(
    const ushort* __restrict__ phk, const ushort* __restrict__ vk,
    const float* __restrict__ vb, float* __restrict__ inv) {
    int b = blockIdx.x;
    int tid = threadIdx.x;
    float p = bf16_to_f32(phk[(size_t)b * H_DIM + tid]);
    float s = -log1pf(-p);
    for (int j = tid; j < V_DIM; j += 256)
        s += bf16_to_f32(vk[(size_t)b * V_DIM + j]) * vb[j];
    for (int off = 32; off > 0; off >>= 1) s += __shfl_down(s, off, 64);
    __shared__ float wsum[4];
    int lane = tid & 63, wid = tid >> 6;
    if (lane == 0) wsum[wid] = s;
    __syncthreads();
    if (tid == 0) {
        float t = wsum[0] + wsum[1] + wsum[2] + wsum[3];
        inv[b] = expf(-t) * (1.0f / 16384.0f);
    }
}

// ---------------- transposes for gw GEMM ----------------
__global__ void build_At(const ushort* __restrict__ P, const float* __restrict__ inv,
                         float sgn, ushort* __restrict__ At) {
    __shared__ float T[64][65];
    int c = threadIdx.x & 63;
    int rb = threadIdx.x >> 6;
    int b0 = blockIdx.x * 64;
    int h0 = blockIdx.y * 64;
    for (int r = rb; r < 64; r += 4) {
        int b = b0 + r;
        T[c][r] = sgn * inv[b] * bf16_to_f32(P[(size_t)b * H_DIM + h0 + c]);
    }
    __syncthreads();
    for (int r = rb; r < 64; r += 4)
        At[(size_t)(h0 + r) * B_DIM + b0 + c] = bf16_rn(T[r][c]);
}

__global__ void build_Bt(const ushort* __restrict__ Sb, const float* __restrict__ Sf,
                         int use_f32, ushort* __restrict__ Bt) {
    __shared__ ushort T[64][65];
    int c = threadIdx.x & 63;
    int rb = threadIdx.x >> 6;
    int b0 = blockIdx.x * 64;
    int v0 = blockIdx.y * 64;
    for (int r = rb; r < 64; r += 4) {
        int b = b0 + r;
        T[c][r] = use_f32 ? bf16_rn(Sf[(size_t)b * V_DIM + v0 + c])
                          : Sb[(size_t)b * V_DIM + v0 + c];
    }
    __syncthreads();
    for (int r = rb; r < 64; r += 4)
        Bt[(size_t)(v0 + r) * B_DIM + b0 + c] = T[r][c];
}

// ---------------- g_vb / g_hb ----------------
__global__ void gvb_kernel(const ushort* __restrict__ vk, const ushort* __restrict__ vbat,
                           const float* __restrict__ inv, float* __restrict__ gvb) {
    int col = blockIdx.x * 256 + threadIdx.x;
    int b0 = blockIdx.y * 512;
    float acc = 0.0f;
    for (int r = 0; r < 512; ++r) {
        int b = b0 + r;
        acc += inv[b] * (bf16_to_f32(vk[(size_t)b * V_DIM + col]) -
                         bf16_to_f32(vbat[(size_t)b * V_DIM + col]));
    }
    atomicAdd(&gvb[col], acc);
}

__global__ void ghb_kernel(const ushort* __restrict__ phk, const ushort* __restrict__ ph0,
                           const float* __restrict__ inv, float* __restrict__ ghb) {
    int col = threadIdx.x;
    int b0 = blockIdx.x * 256;
    float acc = 0.0f;
    for (int r = 0; r < 256; ++r) {
        int b = b0 + r;
        acc += inv[b] * (bf16_to_f32(phk[(size_t)b * H_DIM + col]) -
                         bf16_to_f32(ph0[(size_t)b * H_DIM + col]));
    }
    atomicAdd(&ghb[col], acc);
}

extern "C" void kernel_launch(void* const* d_in, const int* in_sizes, int n_in,
                              void* d_out, int out_size, void* d_ws, size_t ws_size,
                              hipStream_t stream) {
    const float* batch = (const float*)d_in[0];
    const float* W = (const float*)d_in[1];
    const float* vb = (const float*)d_in[2];
    const float* hb = (const float*)d_in[3];

    char* base = (char*)d_ws;
    ushort* w_hi  = (ushort*)(base + 0);          // 512 KB
    ushort* w_lo  = (ushort*)(base + 524288);
    ushort* v_cur = (ushort*)(base + 2097152);    // 32 MB
    float*  inv   = (float*)(base + 35651584);    // 64 KB
    ushort* At    = (ushort*)(base + 35717120);   // 8 MB
    ushort* batch_bf = (ushort*)(base + 44105728); // 32 MB (aliased: Bt after last use)
    ushort* Bt    = batch_bf;
    ushort* ph0b  = (ushort*)(base + 77660160);   // 8 MB
    ushort* phkb  = (ushort*)(base + 86048768);   // 8 MB -> total 94437376 B

    float* gw  = (float*)d_out;
    float* gvb = gw + (size_t)H_DIM * V_DIM;
    float* ghb = gvb + V_DIM;

    hipMemsetAsync(d_out, 0, (size_t)out_size * sizeof(float), stream);

    // Partitionable threefry split of key(42): subkey[n] = threefry((0,42),(0,n)).
    KeyPack kp;
    for (int i = 0; i < K_STEPS; ++i) {
        threefry2x32(0u, 42u, 0u, (uint32_t)(2 * i),     &kp.hk0[i], &kp.hk1[i]);
        threefry2x32(0u, 42u, 0u, (uint32_t)(2 * i + 1), &kp.vk0[i], &kp.vk1[i]);
    }

    wsplit_kernel<<<dim3(1024), dim3(256), 0, stream>>>(W, w_hi, w_lo);
    tobf16_kernel<<<dim3(B_DIM * V_DIM / 4 / 256), dim3(256), 0, stream>>>(batch, batch_bf);

    // Entire k=8 Gibbs chain + final phk pass, fused (rows are independent).
    gibbs_fused<<<dim3(B_DIM / 32), dim3(512), 0, stream>>>(
        batch_bf, w_hi, w_lo, W, vb, hb, v_cur, ph0b, phkb, kp);

    lognorm_kernel<<<dim3(B_DIM), dim3(256), 0, stream>>>(phkb, v_cur, vb, inv);
    ghb_kernel<<<dim3(B_DIM / 256), dim3(256), 0, stream>>>(phkb, ph0b, inv, ghb);
    gvb_kernel<<<dim3(V_DIM / 256, B_DIM / 512), dim3(256), 0, stream>>>(v_cur, batch_bf, inv, gvb);

    // g_W positive phase
    build_At<<<dim3(B_DIM / 64, H_DIM / 64), dim3(256), 0, stream>>>(phkb, inv, 1.0f, At);
    build_Bt<<<dim3(B_DIM / 64, V_DIM / 64), dim3(256), 0, stream>>>(v_cur, nullptr, 0, Bt);
    mfma_gemm_acc<<<dim3(H_DIM / 64, V_DIM / 64, 16), dim3(256), 0, stream>>>(
        At, Bt, gw, V_DIM, B_DIM, 1024);
    // g_W negative phase
    build_At<<<dim3(B_DIM / 64, H_DIM / 64), dim3(256), 0, stream>>>(ph0b, inv, -1.0f, At);
    build_Bt<<<dim3(B_DIM / 64, V_DIM / 64), dim3(256), 0, stream>>>(nullptr, batch, 1, Bt);
    mfma_gemm_acc<<<dim3(H_DIM / 64, V_DIM / 64, 16), dim3(256), 0, stream>>>(
        At, Bt, gw, V_DIM, B_DIM, 1024);
}

// Round 4
// 859.176 us; speedup vs baseline: 1.9377x; 1.4674x over previous
//
#include <hip/hip_runtime.h>
#include <stdint.h>

#define B_DIM 16384
#define V_DIM 1024
#define H_DIM 256
#define K_STEPS 8
#define HALF_B 8192

typedef short bf16x8 __attribute__((ext_vector_type(8)));
typedef float f32x4 __attribute__((ext_vector_type(4)));

// ---------------- Threefry-2x32-20, bit-exact JAX replica ----------------
__host__ __device__ inline uint32_t rotl32(uint32_t v, int r) {
#if defined(__HIP_DEVICE_COMPILE__)
    return __builtin_amdgcn_alignbit(v, v, (uint32_t)(32 - r));
#else
    return (v << r) | (v >> (32 - r));
#endif
}

__host__ __device__ inline void threefry2x32(uint32_t k0, uint32_t k1,
                                             uint32_t x0, uint32_t x1,
                                             uint32_t* o0, uint32_t* o1) {
    uint32_t k2 = k0 ^ k1 ^ 0x1BD11BDAu;
    x0 += k0; x1 += k1;
#define TF_RND(r) { x0 += x1; x1 = rotl32(x1, (r)); x1 ^= x0; }
    TF_RND(13) TF_RND(15) TF_RND(26) TF_RND(6)
    x0 += k1; x1 += k2 + 1u;
    TF_RND(17) TF_RND(29) TF_RND(16) TF_RND(24)
    x0 += k2; x1 += k0 + 2u;
    TF_RND(13) TF_RND(15) TF_RND(26) TF_RND(6)
    x0 += k0; x1 += k1 + 3u;
    TF_RND(17) TF_RND(29) TF_RND(16) TF_RND(24)
    x0 += k1; x1 += k2 + 4u;
    TF_RND(13) TF_RND(15) TF_RND(26) TF_RND(6)
    x0 += k2; x1 += k0 + 5u;
#undef TF_RND
    *o0 = x0; *o1 = x1;
}

// Partitionable-threefry uniform (bits = o0 ^ o1 of counter (0, e)).
__device__ inline float tf_uniform(uint32_t key0, uint32_t key1, uint32_t e) {
    uint32_t o0, o1;
    threefry2x32(key0, key1, 0u, e, &o0, &o1);
    uint32_t bits = o0 ^ o1;
    return __uint_as_float((bits >> 9) | 0x3f800000u) - 1.0f;
}

__device__ inline uint16_t bf16_rn(float f) {
    uint32_t u = __float_as_uint(f);
    uint32_t r = u + 0x7FFFu + ((u >> 16) & 1u);
    return (uint16_t)(r >> 16);
}
__device__ inline float bf16_to_f32(uint16_t h) {
    return __uint_as_float(((uint32_t)h) << 16);
}

__device__ inline void gload_lds16(const void* g, void* l) {
    __builtin_amdgcn_global_load_lds((const __attribute__((address_space(1))) uint32_t*)g,
                                     (__attribute__((address_space(3))) uint32_t*)l, 16, 0, 0);
}

// ---------------- GEMM block body (R0 math, XOR-swizzled merged LDS tiles) --------
// C[64 x 64] tile of A[M x K] * Bt[N x K]^T (+bias). 4 waves, each 32x32 (2x2 frags).
// LDS: Am [64 rows][128 B] slots {s b2, q b1:0} ^ (row&7)        (8 KB)
//      Bm [64 rows][256 B] slots {s b3, hl b2, q b1:0} ^ (row&15) (16 KB)
// Staging keeps LINEAR gload_lds destinations; the per-lane GLOBAL source is
// pre-swizzled (rule #21 both-sides, conflict scheme verified in R2: 41x down).
// Frag reads land 2 lanes/bank-group = free. MFMA inputs and accumulation order
// are bit-identical to the round-0 kernel.
template <int MODE>
__device__ __forceinline__ void gemm_block(
    const int m0, const int n0,
    const ushort* __restrict__ A, const ushort* __restrict__ Bhi,
    const ushort* __restrict__ Blo, const float* __restrict__ bias,
    ushort* __restrict__ out, ushort* __restrict__ out2,
    const int N, const int K, const uint32_t key0, const uint32_t key1,
    ushort* Am, ushort* Bm) {
    const int tid = threadIdx.x;
    const int lane = tid & 63;
    const int w = tid >> 6;            // 0..3
    const int wm = (w & 1) * 32;
    const int wn = (w >> 1) * 32;
    const int q = lane >> 4;
    const int l15 = lane & 15;

    // staging sources (k0-invariant). A: issue j=w*2+i covers rows j*8..+7.
    const ushort* asrc[2];
#pragma unroll
    for (int i = 0; i < 2; ++i) {
        const int j = w * 2 + i;
        const int row = j * 8 + (lane >> 3);
        const int sl = (lane & 7) ^ (row & 7);
        asrc[i] = A + (size_t)(m0 + row) * K + (sl >> 2) * 32 + (sl & 3) * 8;
    }
    // B: issue j=w*4+i covers rows j*4..+3 (hi+lo merged per row).
    const ushort* bsrc[4];
#pragma unroll
    for (int i = 0; i < 4; ++i) {
        const int j = w * 4 + i;
        const int row = j * 4 + (lane >> 4);
        const int sl = (lane & 15) ^ (row & 15);
        const int hl = (sl >> 2) & 1;
        bsrc[i] = (hl ? Blo : Bhi) + (size_t)(n0 + row) * K + (sl >> 3) * 32 + (sl & 3) * 8;
    }

    f32x4 acc[2][2] = {};

    for (int k0 = 0; k0 < K; k0 += 64) {
#pragma unroll
        for (int i = 0; i < 2; ++i)
            gload_lds16(asrc[i] + k0, &Am[(w * 2 + i) * 512]);
#pragma unroll
        for (int i = 0; i < 4; ++i)
            gload_lds16(bsrc[i] + k0, &Bm[(w * 4 + i) * 512]);
        __syncthreads();
#pragma unroll
        for (int s = 0; s < 2; ++s) {
            bf16x8 af[2], bh[2], bl[2];
#pragma unroll
            for (int i = 0; i < 2; ++i) {
                const int ra = wm + i * 16 + l15;
                af[i] = *(const bf16x8*)((const char*)Am + ra * 128 +
                                         (((s * 4 + q) ^ (ra & 7)) * 16));
            }
#pragma unroll
            for (int j = 0; j < 2; ++j) {
                const int rb = wn + j * 16 + l15;
                const char* bb = (const char*)Bm + rb * 256;
                bh[j] = *(const bf16x8*)(bb + (((s * 8 + q) ^ (rb & 15)) * 16));
                bl[j] = *(const bf16x8*)(bb + (((s * 8 + 4 + q) ^ (rb & 15)) * 16));
            }
#pragma unroll
            for (int i = 0; i < 2; ++i)
#pragma unroll
                for (int j = 0; j < 2; ++j) {
                    acc[i][j] = __builtin_amdgcn_mfma_f32_16x16x32_bf16(af[i], bh[j], acc[i][j], 0, 0, 0);
                    acc[i][j] = __builtin_amdgcn_mfma_f32_16x16x32_bf16(af[i], bl[j], acc[i][j], 0, 0, 0);
                }
        }
        __syncthreads();
    }

    const int orow = q * 4;
#pragma unroll
    for (int i = 0; i < 2; ++i) {
#pragma unroll
        for (int j = 0; j < 2; ++j) {
            int col = n0 + wn + j * 16 + l15;
            float bv = bias[col];
#pragma unroll
            for (int r = 0; r < 4; ++r) {
                int row = m0 + wm + i * 16 + orow + r;
                float val = acc[i][j][r] + bv;
                if (MODE == 0) {
                    float E = expf(-val);
                    uint32_t e = (uint32_t)row * (uint32_t)N + (uint32_t)col;
                    float u = tf_uniform(key0, key1, e);
                    out[(size_t)row * N + col] = (fmaf(u, E, u) < 1.0f) ? (ushort)0x3F80 : (ushort)0;
                } else if (MODE == 3) {
                    float E = expf(-val);
                    float sg = 1.0f / (1.0f + E);
                    uint32_t e = (uint32_t)row * (uint32_t)N + (uint32_t)col;
                    float u = tf_uniform(key0, key1, e);
                    out[(size_t)row * N + col] = (fmaf(u, E, u) < 1.0f) ? (ushort)0x3F80 : (ushort)0;
                    out2[(size_t)row * N + col] = bf16_rn(sg);
                } else {
                    float sg = 1.0f / (1.0f + expf(-val));
                    out[(size_t)row * N + col] = bf16_rn(sg);
                }
            }
        }
    }
}

// ---------------- Sparse v-side sampler body (round-0 proven, fma-compare) -------
__device__ __forceinline__ void vsample_block(
    const ushort* __restrict__ h, const float* __restrict__ W,
    const float* __restrict__ vb, ushort* __restrict__ vout,
    uint32_t key0, uint32_t key1, int row_base) {
    const int lane = threadIdx.x & 63;
    const int wid = threadIdx.x >> 6;

    float vbr[16];
#pragma unroll
    for (int t = 0; t < 16; ++t) vbr[t] = vb[lane + 64 * t];

    const int rb2 = row_base + wid * 2;
#pragma unroll
    for (int rr = 0; rr < 2; ++rr) {
        const int b = rb2 + rr;
        ushort4 hv = ((const ushort4*)(h + (size_t)b * H_DIM))[lane];
        unsigned long long masks[4];
        masks[0] = __ballot(hv.x != 0);
        masks[1] = __ballot(hv.y != 0);
        masks[2] = __ballot(hv.z != 0);
        masks[3] = __ballot(hv.w != 0);

        float acc[16];
#pragma unroll
        for (int t = 0; t < 16; ++t) acc[t] = 0.0f;

#pragma unroll
        for (int s = 0; s < 4; ++s) {
            unsigned long long m = masks[s];
            while (m) {  // wave-uniform loop, no divergence
                int l = __ffsll(m) - 1;
                m &= m - 1;
                int j = l * 4 + s;
                const float* wrow = W + (size_t)j * V_DIM + lane;
#pragma unroll
                for (int t = 0; t < 16; ++t) acc[t] += wrow[64 * t];
            }
        }

        const uint32_t ebase = (uint32_t)b * (uint32_t)V_DIM + (uint32_t)lane;
        ushort* orow = vout + (size_t)b * V_DIM + lane;
#pragma unroll
        for (int t = 0; t < 16; ++t) {
            float pre = acc[t] + vbr[t];
            float E = expf(-pre);
            float u = tf_uniform(key0, key1, ebase + 64u * (uint32_t)t);
            orow[64 * t] = (fmaf(u, E, u) < 1.0f) ? (ushort)0x3F80 : (ushort)0;
        }
    }
}

// ---------------- Standalone half-batch GEMM (slots 0 and 17) ----------------
template <int MODE>
__global__ __launch_bounds__(256, 4) void gemm_only(
    const ushort* __restrict__ A, const ushort* __restrict__ Bhi,
    const ushort* __restrict__ Blo, const float* __restrict__ bias,
    ushort* __restrict__ out, ushort* __restrict__ out2,
    uint32_t key0, uint32_t key1, int mbase) {
    __shared__ __align__(16) ushort Am[64 * 64];
    __shared__ __align__(16) ushort Bm[64 * 128];
    gemm_block<MODE>(mbase + blockIdx.x * 64, blockIdx.y * 64, A, Bhi, Blo, bias,
                     out, out2, H_DIM, V_DIM, key0, key1, Am, Bm);
}

// ---------------- Hybrid dispatch: vsample(half X, step s') || hgemm(half Y, s) ---
// Two INDEPENDENT proven workloads (disjoint batch rows) co-dispatched so MFMA-
// blocks and VALU-RNG-blocks are co-resident on every CU (m114 overlap), on one
// stream, graph-safe. vsample blocks first (longer pole starts earlier).
template <int MODE>
__global__ __launch_bounds__(256, 4) void hybrid_step(
    // gemm part (half at gemm_mbase)
    const ushort* __restrict__ vin, const ushort* __restrict__ Whi,
    const ushort* __restrict__ Wlo, const float* __restrict__ hb,
    ushort* __restrict__ hout, ushort* __restrict__ out2,
    uint32_t gk0, uint32_t gk1, int gemm_mbase,
    // vsample part (half at vs_base)
    const ushort* __restrict__ hprev, const float* __restrict__ Wf,
    const float* __restrict__ vb, ushort* __restrict__ vout,
    uint32_t vk0, uint32_t vk1, int vs_base, int nb_vs) {
    __shared__ __align__(16) ushort Am[64 * 64];
    __shared__ __align__(16) ushort Bm[64 * 128];
    const int bid = blockIdx.x;
    if (bid < nb_vs) {
        vsample_block(hprev, Wf, vb, vout, vk0, vk1, vs_base + bid * 8);
    } else {
        const int g = bid - nb_vs;
        const int gx = g & 127;        // 8192/64 = 128 m-blocks
        const int gy = g >> 7;         // 4 n-blocks
        gemm_block<MODE>(gemm_mbase + gx * 64, gy * 64, vin, Whi, Wlo, hb,
                         hout, out2, H_DIM, V_DIM, gk0, gk1, Am, Bm);
    }
}

// ---------------- LDS MFMA NT-GEMM accumulate (gw), swizzled tiles ----------------
__global__ __launch_bounds__(256, 4) void mfma_gemm_acc(
    const ushort* __restrict__ A, const ushort* __restrict__ Bt,
    float* __restrict__ out, int N, int K, int k_slice) {
    __shared__ __align__(16) ushort As[64 * 64];   // [64 rows][128 B], A-scheme swizzle
    __shared__ __align__(16) ushort Bs[64 * 64];

    const int tid = threadIdx.x;
    const int lane = tid & 63;
    const int w = tid >> 6;
    const int m0 = blockIdx.x * 64;
    const int n0 = blockIdx.y * 64;
    const int kbase = blockIdx.z * k_slice;

    const int wm = (w & 1) * 32;
    const int wn = (w >> 1) * 32;
    const int q = lane >> 4;
    const int l15 = lane & 15;

    const ushort* asrc[2];
    const ushort* bsrc[2];
#pragma unroll
    for (int i = 0; i < 2; ++i) {
        const int j = w * 2 + i;
        const int row = j * 8 + (lane >> 3);
        const int sl = (lane & 7) ^ (row & 7);
        const size_t off = (size_t)row * K + (sl >> 2) * 32 + (sl & 3) * 8;
        asrc[i] = A + (size_t)m0 * K + off;
        bsrc[i] = Bt + (size_t)n0 * K + off;
    }

    f32x4 acc[2][2] = {};

    for (int kt = 0; kt < k_slice; kt += 64) {
        const int k0 = kbase + kt;
#pragma unroll
        for (int i = 0; i < 2; ++i) {
            gload_lds16(asrc[i] + k0, &As[(w * 2 + i) * 512]);
            gload_lds16(bsrc[i] + k0, &Bs[(w * 2 + i) * 512]);
        }
        __syncthreads();
#pragma unroll
        for (int s = 0; s < 2; ++s) {
            bf16x8 af[2], bf[2];
#pragma unroll
            for (int i = 0; i < 2; ++i) {
                const int ra = wm + i * 16 + l15;
                const int rb = wn + i * 16 + l15;
                af[i] = *(const bf16x8*)((const char*)As + ra * 128 +
                                         (((s * 4 + q) ^ (ra & 7)) * 16));
                bf[i] = *(const bf16x8*)((const char*)Bs + rb * 128 +
                                         (((s * 4 + q) ^ (rb & 7)) * 16));
            }
#pragma unroll
            for (int i = 0; i < 2; ++i)
#pragma unroll
                for (int j = 0; j < 2; ++j)
                    acc[i][j] = __builtin_amdgcn_mfma_f32_16x16x32_bf16(af[i], bf[j], acc[i][j], 0, 0, 0);
        }
        __syncthreads();
    }

    const int orow = q * 4;
#pragma unroll
    for (int i = 0; i < 2; ++i)
#pragma unroll
        for (int j = 0; j < 2; ++j) {
            int col = n0 + wn + j * 16 + l15;
#pragma unroll
            for (int r = 0; r < 4; ++r) {
                int row = m0 + wm + i * 16 + orow + r;
                atomicAdd(&out[(size_t)row * N + col], acc[i][j][r]);
            }
        }
}

// ---------------- W split into bf16 hi/lo ----------------
__global__ void wsplit_kernel(const float* __restrict__ W, ushort* __restrict__ whi,
                              ushort* __restrict__ wlo) {
    int idx = blockIdx.x * 256 + threadIdx.x;
    float w = W[idx];
    ushort hi = bf16_rn(w);
    float fhi = bf16_to_f32(hi);
    ushort lo = bf16_rn(w - fhi);
    whi[idx] = hi; wlo[idx] = lo;
}

__global__ void tobf16_kernel(const float* __restrict__ src, ushort* __restrict__ dst) {
    int idx = blockIdx.x * 256 + threadIdx.x;
    float4 f = ((const float4*)src)[idx];
    ushort4 o;
    o.x = bf16_rn(f.x); o.y = bf16_rn(f.y); o.z = bf16_rn(f.z); o.w = bf16_rn(f.w);
    ((ushort4*)dst)[idx] = o;
}

// ---------------- log-norm ----------------
__global__ __launch_bounds__(256) void lognorm_kernel(
    const ushort* __restrict__ phk, const ushort* __restrict__ vk,
    const float* __restrict__ vb, float* __restrict__ inv) {
    int b = blockIdx.x;
    int tid = threadIdx.x;
    float p = bf16_to_f32(phk[(size_t)b * H_DIM + tid]);
    float s = -log1pf(-p);
    for (int j = tid; j < V_DIM; j += 256)
        s += bf16_to_f32(vk[(size_t)b * V_DIM + j]) * vb[j];
    for (int off = 32; off > 0; off >>= 1) s += __shfl_down(s, off, 64);
    __shared__ float wsum[4];
    int lane = tid & 63, wid = tid >> 6;
    if (lane == 0) wsum[wid] = s;
    __syncthreads();
    if (tid == 0) {
        float t = wsum[0] + wsum[1] + wsum[2] + wsum[3];
        inv[b] = expf(-t) * (1.0f / 16384.0f);
    }
}

// ---------------- transposes for gw GEMM ----------------
__global__ void build_At(const ushort* __restrict__ P, const float* __restrict__ inv,
                         float sgn, ushort* __restrict__ At) {
    __shared__ float T[64][65];
    int c = threadIdx.x & 63;
    int rb = threadIdx.x >> 6;
    int b0 = blockIdx.x * 64;
    int h0 = blockIdx.y * 64;
    for (int r = rb; r < 64; r += 4) {
        int b = b0 + r;
        T[c][r] = sgn * inv[b] * bf16_to_f32(P[(size_t)b * H_DIM + h0 + c]);
    }
    __syncthreads();
    for (int r = rb; r < 64; r += 4)
        At[(size_t)(h0 + r) * B_DIM + b0 + c] = bf16_rn(T[r][c]);
}

__global__ void build_Bt(const ushort* __restrict__ Sb, const float* __restrict__ Sf,
                         int use_f32, ushort* __restrict__ Bt) {
    __shared__ ushort T[64][65];
    int c = threadIdx.x & 63;
    int rb = threadIdx.x >> 6;
    int b0 = blockIdx.x * 64;
    int v0 = blockIdx.y * 64;
    for (int r = rb; r < 64; r += 4) {
        int b = b0 + r;
        T[c][r] = use_f32 ? bf16_rn(Sf[(size_t)b * V_DIM + v0 + c])
                          : Sb[(size_t)b * V_DIM + v0 + c];
    }
    __syncthreads();
    for (int r = rb; r < 64; r += 4)
        Bt[(size_t)(v0 + r) * B_DIM + b0 + c] = T[r][c];
}

// ---------------- g_vb / g_hb ----------------
__global__ void gvb_kernel(const ushort* __restrict__ vk, const ushort* __restrict__ vbat,
                           const float* __restrict__ inv, float* __restrict__ gvb) {
    int col = blockIdx.x * 256 + threadIdx.x;
    int b0 = blockIdx.y * 512;
    float acc = 0.0f;
    for (int r = 0; r < 512; ++r) {
        int b = b0 + r;
        acc += inv[b] * (bf16_to_f32(vk[(size_t)b * V_DIM + col]) -
                         bf16_to_f32(vbat[(size_t)b * V_DIM + col]));
    }
    atomicAdd(&gvb[col], acc);
}

__global__ void ghb_kernel(const ushort* __restrict__ phk, const ushort* __restrict__ ph0,
                           const float* __restrict__ inv, float* __restrict__ ghb) {
    int col = threadIdx.x;
    int b0 = blockIdx.x * 256;
    float acc = 0.0f;
    for (int r = 0; r < 256; ++r) {
        int b = b0 + r;
        acc += inv[b] * (bf16_to_f32(phk[(size_t)b * H_DIM + col]) -
                         bf16_to_f32(ph0[(size_t)b * H_DIM + col]));
    }
    atomicAdd(&ghb[col], acc);
}

extern "C" void kernel_launch(void* const* d_in, const int* in_sizes, int n_in,
                              void* d_out, int out_size, void* d_ws, size_t ws_size,
                              hipStream_t stream) {
    const float* batch = (const float*)d_in[0];
    const float* W = (const float*)d_in[1];
    const float* vb = (const float*)d_in[2];
    const float* hb = (const float*)d_in[3];

    char* base = (char*)d_ws;
    ushort* w_hi  = (ushort*)(base + 0);          // 512 KB
    ushort* w_lo  = (ushort*)(base + 524288);
    ushort* v_cur = (ushort*)(base + 2097152);    // 32 MB
    float*  inv   = (float*)(base + 35651584);    // 64 KB
    ushort* h_cur = (ushort*)(base + 35717120);   // 8 MB (aliased: At after chain)
    ushort* At    = h_cur;
    ushort* batch_bf = (ushort*)(base + 44105728); // 32 MB (aliased: Bt after last use)
    ushort* Bt    = batch_bf;
    ushort* ph0b  = (ushort*)(base + 77660160);   // 8 MB
    ushort* phkb  = (ushort*)(base + 86048768);   // 8 MB -> total 94437376 B

    float* gw  = (float*)d_out;
    float* gvb = gw + (size_t)H_DIM * V_DIM;
    float* ghb = gvb + V_DIM;

    hipMemsetAsync(d_out, 0, (size_t)out_size * sizeof(float), stream);

    // Partitionable threefry split of key(42): subkey[n] = threefry((0,42),(0,n)).
    uint32_t sk0[16], sk1[16];
    for (int n = 0; n < 16; ++n) threefry2x32(0u, 42u, 0u, (uint32_t)n, &sk0[n], &sk1[n]);

    wsplit_kernel<<<dim3(1024), dim3(256), 0, stream>>>(W, w_hi, w_lo);
    tobf16_kernel<<<dim3(B_DIM * V_DIM / 4 / 256), dim3(256), 0, stream>>>(batch, batch_bf);

    const int NB_VS = HALF_B / 8;          // 1024 vsample blocks per half
    const int NB_G  = (HALF_B / 64) * 4;   // 512 gemm blocks per half
    const dim3 HYB(NB_VS + NB_G);

    // slot 0: gemm(half0, step0, MODE3)
    gemm_only<3><<<dim3(128, 4), dim3(256), 0, stream>>>(
        batch_bf, w_hi, w_lo, hb, h_cur, ph0b, sk0[0], sk1[0], 0);

    for (int s = 0; s < K_STEPS; ++s) {
        const ushort* vin = (s == 0) ? batch_bf : v_cur;
        // slot 2s+1: gemm(half1, step s) || vsample(half0, step s)
        if (s == 0) {
            hybrid_step<3><<<HYB, dim3(256), 0, stream>>>(
                vin, w_hi, w_lo, hb, h_cur, ph0b, sk0[0], sk1[0], HALF_B,
                h_cur, W, vb, v_cur, sk0[1], sk1[1], 0, NB_VS);
        } else {
            hybrid_step<0><<<HYB, dim3(256), 0, stream>>>(
                vin, w_hi, w_lo, hb, h_cur, nullptr, sk0[2 * s], sk1[2 * s], HALF_B,
                h_cur, W, vb, v_cur, sk0[2 * s + 1], sk1[2 * s + 1], 0, NB_VS);
        }
        // slot 2s+2: gemm(half0, step s+1 | final) || vsample(half1, step s)
        if (s < K_STEPS - 1) {
            hybrid_step<0><<<HYB, dim3(256), 0, stream>>>(
                v_cur, w_hi, w_lo, hb, h_cur, nullptr, sk0[2 * s + 2], sk1[2 * s + 2], 0,
                h_cur, W, vb, v_cur, sk0[2 * s + 1], sk1[2 * s + 1], HALF_B, NB_VS);
        } else {
            hybrid_step<1><<<HYB, dim3(256), 0, stream>>>(
                v_cur, w_hi, w_lo, hb, phkb, nullptr, 0u, 0u, 0,
                h_cur, W, vb, v_cur, sk0[2 * s + 1], sk1[2 * s + 1], HALF_B, NB_VS);
        }
    }
    // slot 17: gemm(half1, final phk, MODE1)
    gemm_only<1><<<dim3(128, 4), dim3(256), 0, stream>>>(
        v_cur, w_hi, w_lo, hb, phkb, nullptr, 0u, 0u, HALF_B);

    lognorm_kernel<<<dim3(B_DIM), dim3(256), 0, stream>>>(phkb, v_cur, vb, inv);
    ghb_kernel<<<dim3(B_DIM / 256), dim3(256), 0, stream>>>(phkb, ph0b, inv, ghb);
    gvb_kernel<<<dim3(V_DIM / 256, B_DIM / 512), dim3(256), 0, stream>>>(v_cur, batch_bf, inv, gvb);

    // g_W positive phase
    build_At<<<dim3(B_DIM / 64, H_DIM / 64), dim3(256), 0, stream>>>(phkb, inv, 1.0f, At);
    build_Bt<<<dim3(B_DIM / 64, V_DIM / 64), dim3(256), 0, stream>>>(v_cur, nullptr, 0, Bt);
    mfma_gemm_acc<<<dim3(H_DIM / 64, V_DIM / 64, 16), dim3(256), 0, stream>>>(
        At, Bt, gw, V_DIM, B_DIM, 1024);
    // g_W negative phase
    build_At<<<dim3(B_DIM / 64, H_DIM / 64), dim3(256), 0, stream>>>(ph0b, inv, -1.0f, At);
    build_Bt<<<dim3(B_DIM / 64, V_DIM / 64), dim3(256), 0, stream>>>(nullptr, batch, 1, Bt);
    mfma_gemm_acc<<<dim3(H_DIM / 64, V_DIM / 64, 16), dim3(256), 0, stream>>>(
        At, Bt, gw, V_DIM, B_DIM, 1024);
}